// Round 8
// baseline (8105.709 us; speedup 1.0000x reference)
//
#include <hip/hip_runtime.h>
#include <math.h>

#pragma clang fp contract(off)

#define NROWS 131072

// selu matching np: scale * where(x>0, x, alpha*expm1(x)), each op rounded separately
__device__ __forceinline__ float selu_f(float v) {
    float em  = expm1f(v);
    float neg = 1.6732632423543772f * em;
    float r   = v > 0.0f ? v : neg;
    return 1.0507009873554805f * r;
}

__device__ __forceinline__ float4 ldf4(const float* p) { return *(const float4*)p; }

__device__ __forceinline__ void ld4x4(float4* b, const float* p) {
    b[0] = ldf4(p); b[1] = ldf4(p + 4); b[2] = ldf4(p + 8); b[3] = ldf4(p + 12);
}

__device__ __forceinline__ void fma16a(float* a, const float4* w, float h) {
    a[0]  = __builtin_fmaf(w[0].x, h, a[0]);  a[1]  = __builtin_fmaf(w[0].y, h, a[1]);
    a[2]  = __builtin_fmaf(w[0].z, h, a[2]);  a[3]  = __builtin_fmaf(w[0].w, h, a[3]);
    a[4]  = __builtin_fmaf(w[1].x, h, a[4]);  a[5]  = __builtin_fmaf(w[1].y, h, a[5]);
    a[6]  = __builtin_fmaf(w[1].z, h, a[6]);  a[7]  = __builtin_fmaf(w[1].w, h, a[7]);
    a[8]  = __builtin_fmaf(w[2].x, h, a[8]);  a[9]  = __builtin_fmaf(w[2].y, h, a[9]);
    a[10] = __builtin_fmaf(w[2].z, h, a[10]); a[11] = __builtin_fmaf(w[2].w, h, a[11]);
    a[12] = __builtin_fmaf(w[3].x, h, a[12]); a[13] = __builtin_fmaf(w[3].y, h, a[13]);
    a[14] = __builtin_fmaf(w[3].z, h, a[14]); a[15] = __builtin_fmaf(w[3].w, h, a[15]);
}

// rotate step: issue next row's 4xf4 loads, then consume current buffer, then rotate in
__device__ __forceinline__ void step16(float* acc, float4* wb, const float* nextp, float h) {
    float4 t0 = ldf4(nextp), t1 = ldf4(nextp + 4), t2 = ldf4(nextp + 8), t3 = ldf4(nextp + 12);
    fma16a(acc, wb, h);
    wb[0] = t0; wb[1] = t1; wb[2] = t2; wb[3] = t3;
}

// 16 fmas from 4 explicit float4s (immediate-consume form, no rotate buffer)
__device__ __forceinline__ void fma16q(float* a, float4 w0, float4 w1, float4 w2, float4 w3, float h) {
    a[0]  = __builtin_fmaf(w0.x, h, a[0]);  a[1]  = __builtin_fmaf(w0.y, h, a[1]);
    a[2]  = __builtin_fmaf(w0.z, h, a[2]);  a[3]  = __builtin_fmaf(w0.w, h, a[3]);
    a[4]  = __builtin_fmaf(w1.x, h, a[4]);  a[5]  = __builtin_fmaf(w1.y, h, a[5]);
    a[6]  = __builtin_fmaf(w1.z, h, a[6]);  a[7]  = __builtin_fmaf(w1.w, h, a[7]);
    a[8]  = __builtin_fmaf(w2.x, h, a[8]);  a[9]  = __builtin_fmaf(w2.y, h, a[9]);
    a[10] = __builtin_fmaf(w2.z, h, a[10]); a[11] = __builtin_fmaf(w2.w, h, a[11]);
    a[12] = __builtin_fmaf(w3.x, h, a[12]); a[13] = __builtin_fmaf(w3.y, h, a[13]);
    a[14] = __builtin_fmaf(w3.z, h, a[14]); a[15] = __builtin_fmaf(w3.w, h, a[15]);
}

// ---------- prep 1: W2 [256,256] -> W2T [j][c]; W3 [64,256] -> W3T [c][e]; W1 [256,64] -> W1T [j][c]
__global__ void prep_transpose(const float* __restrict__ W1, const float* __restrict__ W2,
                               const float* __restrict__ W3,
                               float* __restrict__ W1T, float* __restrict__ W2T,
                               float* __restrict__ W3T) {
    int id = blockIdx.x * 256 + threadIdx.x;
    if (id < 65536) { int c = id >> 8, j = id & 255; W2T[j * 256 + c] = W2[id]; }
    int id2 = id - 65536;
    if (id2 >= 0 && id2 < 16384) { int e = id2 >> 8, c = id2 & 255; W3T[c * 64 + e] = W3[id2]; }
    int id3 = id - 81920;
    if (id3 >= 0 && id3 < 16384) { int c = id3 >> 6, j = id3 & 63; W1T[j * 256 + c] = W1[id3]; }
}

// ---------- prep 2: decoder table dec_out[k] = decoder(emb[k]), and en[k] = ||emb_k||^2 ----------
__global__ void prep_decoder(const float* __restrict__ emb,
                             const float* __restrict__ Wd1, const float* __restrict__ bd1,
                             const float* __restrict__ Wd2, const float* __restrict__ bd2,
                             const float* __restrict__ Wd3, const float* __restrict__ bd3,
                             float* __restrict__ dec_out, float* __restrict__ en) {
    __shared__ float e[64];
    __shared__ float h1[256];
    __shared__ float h2[256];
    const int t = threadIdx.x; // 256 threads
    for (int kc = 0; kc < 4; ++kc) {
        const int k = blockIdx.x * 4 + kc;
        __syncthreads();
        if (t < 64) e[t] = emb[k * 64 + t];
        __syncthreads();
        {
            float acc = 0.0f;
            const float* w = Wd1 + t * 64;
            #pragma unroll
            for (int j = 0; j < 64; ++j) acc = __builtin_fmaf(w[j], e[j], acc);
            h1[t] = selu_f(acc + bd1[t]);
        }
        __syncthreads();
        {
            float acc = 0.0f;
            const float* w = Wd2 + t * 256;
            #pragma unroll 8
            for (int j = 0; j < 256; ++j) acc = __builtin_fmaf(w[j], h1[j], acc);
            h2[t] = selu_f(acc + bd2[t]);
        }
        __syncthreads();
        if (t < 64) {
            float acc = 0.0f;
            const float* w = Wd3 + t * 256;
            #pragma unroll 8
            for (int j = 0; j < 256; ++j) acc = __builtin_fmaf(w[j], h2[j], acc);
            dec_out[k * 64 + t] = acc + bd3[t];
        }
        if (t == 0) {
            float r[8];
            #pragma unroll
            for (int u = 0; u < 8; ++u) r[u] = e[u] * e[u];
            #pragma unroll
            for (int i = 8; i < 64; i += 8) {
                #pragma unroll
                for (int u = 0; u < 8; ++u) { float p = e[i + u] * e[i + u]; r[u] = r[u] + p; }
            }
            en[k] = ((r[0] + r[1]) + (r[2] + r[3])) + ((r[4] + r[5]) + (r[6] + r[7]));
        }
    }
}

// ---------- main kernel ----------
// 256 threads = 4 waves, 64 rows (lane = row).
// OCCUPANCY LAW (rounds 0-7): waves/SIMD = 512/(2*VGPR) for wave64 -> VGPR=128 gives 2
// waves/SIMD no matter what attributes/LDS say. So this round attacks the per-wave stall
// instead: phases 2 and 4 streamed weights/emb with lane-redundant uniform VMEM loads
// (all 64 lanes load the same address, immediate-consume) -> every 4 FMAs exposed a full
// L2 round-trip. Now each wave cooperatively stages its own sub-chunk into a PRIVATE LDS
// region (coalesced 2xf4/lane, double-buffered: global latency hides under the previous
// sub-chunk's 512 FMAs) and consumes via LDS broadcast reads. No cross-wave barriers.
// Staging changes only WHERE data is read from; all FMA chain orders identical -> bit-exact.
// LDS: B0 16 KB (xT -> fold stage -> emb stage -> cand) + B1 17 KB + B2 16 KB (W2 stage) = 49 KB
// (costless: VGPR=128 caps at 2 blocks/CU anyway).
__global__ __launch_bounds__(256) __attribute__((amdgpu_waves_per_eu(2, 8)))
void vqvae_main(const float* __restrict__ x,
                const float* __restrict__ b1, const float* __restrict__ b2,
                const float* __restrict__ b3,
                const float* __restrict__ W1T, const float* __restrict__ W2T,
                const float* __restrict__ W3T,
                const float* __restrict__ emb, const float* __restrict__ en,
                const float* __restrict__ dec_out, float* __restrict__ out) {
    __shared__ __align__(16) float B0[4096];   // xT (ph0-1) -> fold stage (ph2b) -> emb stage (ph4) -> cand (ph5)
    __shared__ __align__(16) float B1[4352];   // h1 chunk, pair layout (ph1-2) -> z park stride 68
    __shared__ __align__(16) float B2[4096];   // W2T stage: per-wave 1024 floats (2 halves x 8 rows x 64 cols)

    const int t    = threadIdx.x;
    const int wave = t >> 6;      // 0..3
    const int lane = t & 63;
    const size_t rowbase = (size_t)blockIdx.x * 64;

    // opaque zero in a VGPR: keeps uniform loads on the vector pipe (vmcnt, pipelinable)
    int lz;
    asm volatile("v_mov_b32 %0, 0" : "=v"(lz));

    const float* W1Tv = W1T + lz;
    const float* W2Tv = W2T + lz;
    const float* W3Tv = W3T + lz;
    const float* b1v  = b1 + lz;
    const float* b2v  = b2 + lz;
    const float* b3v  = b3 + lz;
    const float* env  = en + lz;
    const float* embv = emb + lz;

    // ---- phase 0: stage x tile transposed into B0: xT[j][r]
    #pragma unroll
    for (int q = 0; q < 4; ++q) {
        int f = t + 256 * q;
        int r = f >> 4, c4 = f & 15;
        float4 v = ldf4(x + (rowbase + r) * 64 + c4 * 4);
        B0[(c4 * 4 + 0) * 64 + r] = v.x;
        B0[(c4 * 4 + 1) * 64 + r] = v.y;
        B0[(c4 * 4 + 2) * 64 + r] = v.z;
        B0[(c4 * 4 + 3) * 64 + r] = v.w;
    }
    __syncthreads();

    // persistent h2 accumulators: wave owns cols [64*wave, 64*wave+64)
    float acc2[64];
    #pragma unroll
    for (int u = 0; u < 64; ++u) acc2[u] = 0.0f;

    // ---- phases 1+2 fused, j-chunked: for each chunk cc, compute h1 cols [64cc,64cc+64)
    // into B1 (pair layout), then accumulate those 64 j's into acc2. j ascending overall.
    for (int cc = 0; cc < 4; ++cc) {
        // phase-1 chunk: wave computes h1 cols cg = 64cc + 16*wave .. +16 (chain: j=0..63 asc)
        {
            const float* wp = W1Tv + cc * 64 + wave * 16;   // row j at wp + j*256
            float4 A[4];
            ld4x4(A, wp);
            float acc[16];
            #pragma unroll
            for (int u = 0; u < 16; ++u) acc[u] = 0.0f;
            #pragma unroll 1
            for (int j = 0; j < 64; ++j) {
                const float* np = wp + (j + 1) * 256;  // j=63 overruns into W3T region (in-ws, unused)
                step16(acc, A, np, B0[j * 64 + lane]);
            }
            float bb[16];
            *(float4*)&bb[0]  = ldf4(b1v + cc * 64 + wave * 16);
            *(float4*)&bb[4]  = ldf4(b1v + cc * 64 + wave * 16 + 4);
            *(float4*)&bb[8]  = ldf4(b1v + cc * 64 + wave * 16 + 8);
            *(float4*)&bb[12] = ldf4(b1v + cc * 64 + wave * 16 + 12);
            float hv[16];
            #pragma unroll
            for (int u = 0; u < 16; ++u) hv[u] = selu_f(acc[u] + bb[u]);
            // pair layout: local j = 16*wave + u; B1[(jl>>1)*128 + 2*lane + (jl&1)]
            #pragma unroll
            for (int up = 0; up < 8; ++up) {
                *(float2*)&B1[(wave * 8 + up) * 128 + (lane << 1)] =
                    make_float2(hv[2 * up], hv[2 * up + 1]);
            }
        }
        __syncthreads();
        // phase-2 chunk (LDS-staged): acc2[u] += sum over this chunk's 64 j's (ascending)
        // of W2T[cc*64+jl][64w+u] * h1[jl]. Wave stages 8-row sub-chunks of its col-quarter
        // into its private B2 region (double-buffered); consume = broadcast LDS reads.
        {
            const float* w2src = W2Tv + (size_t)(cc * 64 + (lane >> 3)) * 256 + wave * 64 + (lane & 7) * 8;
            float* stw = B2 + wave * 1024 + (lane >> 3) * 64 + (lane & 7) * 8;
            {   // prologue: sub-chunk 0 -> half 0
                float4 sa = ldf4(w2src), sb = ldf4(w2src + 4);
                *(float4*)(stw) = sa; *(float4*)(stw + 4) = sb;
            }
            #pragma unroll 1
            for (int s = 0; s < 8; ++s) {
                const int cur = s & 1;
                float4 na, nb;
                if (s < 7) {    // issue next sub-chunk's loads; they fly under the FMAs below
                    na = ldf4(w2src + (s + 1) * 2048);
                    nb = ldf4(w2src + (s + 1) * 2048 + 4);
                }
                const float* wl = B2 + wave * 1024 + cur * 512;   // [row 0..7][col 0..63]
                #pragma unroll
                for (int jj = 0; jj < 8; jj += 2) {
                    float2 h01 = *(const float2*)&B1[((s * 8 + jj) >> 1) * 128 + (lane << 1)];
                    const float* r0 = wl + jj * 64;
                    #pragma unroll
                    for (int qd = 0; qd < 4; ++qd) {
                        const float* p = r0 + qd * 16;
                        fma16q(acc2 + qd * 16, ldf4(p), ldf4(p + 4), ldf4(p + 8), ldf4(p + 12), h01.x);
                    }
                    const float* r1 = wl + (jj + 1) * 64;
                    #pragma unroll
                    for (int qd = 0; qd < 4; ++qd) {
                        const float* p = r1 + qd * 16;
                        fma16q(acc2 + qd * 16, ldf4(p), ldf4(p + 4), ldf4(p + 8), ldf4(p + 12), h01.y);
                    }
                }
                if (s < 7) {
                    float* stn = stw + ((cur ^ 1) * 512);
                    *(float4*)(stn) = na; *(float4*)(stn + 4) = nb;
                }
            }
        }
        __syncthreads();   // h1 consumed; next chunk may overwrite (also guards B0 reuse later)
    }

    // h2 = selu(acc2 + b2) in place
    {
        #pragma unroll
        for (int qd = 0; qd < 4; ++qd) {
            float bb[16];
            *(float4*)&bb[0]  = ldf4(b2v + wave * 64 + qd * 16);
            *(float4*)&bb[4]  = ldf4(b2v + wave * 64 + qd * 16 + 4);
            *(float4*)&bb[8]  = ldf4(b2v + wave * 64 + qd * 16 + 8);
            *(float4*)&bb[12] = ldf4(b2v + wave * 64 + qd * 16 + 12);
            #pragma unroll
            for (int i = 0; i < 16; ++i)
                acc2[qd * 16 + i] = selu_f(acc2[qd * 16 + i] + bb[i]);
        }
    }

    // ---- phase 2b: layer-3 fold, staged per col-block g (= wave g's h2 cols), c ascending.
    // z = ((P0+P1)+(P2+P3)) + b3 (identical combine to all passing rounds)
    const int er = wave * 16;
    float s01[16], s23[16];
    for (int g = 0; g < 4; ++g) {
        if (wave == g) {
            #pragma unroll
            for (int u = 0; u < 64; ++u) B0[u * 64 + lane] = acc2[u];
        }
        __syncthreads();   // stage visible to all
        const float* w3p = W3Tv + g * 4096 + er;    // col (64g+c) at w3p + c*64
        float4 F0[4], F1[4];
        ld4x4(F0, w3p); ld4x4(F1, w3p + 64);
        float P[16];
        #pragma unroll
        for (int u = 0; u < 16; ++u) P[u] = 0.0f;
        #pragma unroll 1
        for (int c = 0; c < 64; c += 2) {
            const float* np = w3p + (c + 2) * 64;  // c=62: rows 64..65 overrun into en pad (in-ws)
            step16(P, F0, np,      B0[(c + 0) * 64 + lane]);
            step16(P, F1, np + 64, B0[(c + 1) * 64 + lane]);
        }
        if (g == 0) {
            #pragma unroll
            for (int u = 0; u < 16; ++u) s01[u] = P[u];
        } else if (g == 1) {
            #pragma unroll
            for (int u = 0; u < 16; ++u) s01[u] = s01[u] + P[u];
        } else if (g == 2) {
            #pragma unroll
            for (int u = 0; u < 16; ++u) s23[u] = P[u];
        } else {
            #pragma unroll
            for (int u = 0; u < 16; ++u) s23[u] = s23[u] + P[u];
        }
        __syncthreads();   // folds done before next wave overwrites stage
    }

    // ---- phase 3: z = (s01+s23)+b3; park z in LDS (zs[lane][e], stride 68 -> 2-way free b128)
    {
        float bb[16];
        *(float4*)&bb[0]  = ldf4(b3v + er);
        *(float4*)&bb[4]  = ldf4(b3v + er + 4);
        *(float4*)&bb[8]  = ldf4(b3v + er + 8);
        *(float4*)&bb[12] = ldf4(b3v + er + 12);
        float zv[16];
        #pragma unroll
        for (int u = 0; u < 16; ++u) zv[u] = (s01[u] + s23[u]) + bb[u];
        #pragma unroll
        for (int m = 0; m < 4; ++m)
            *(float4*)&B1[lane * 68 + er + m * 4] =
                make_float4(zv[4 * m], zv[4 * m + 1], zv[4 * m + 2], zv[4 * m + 3]);
    }
    __syncthreads();

    // ---- phase 4 staging setup: wave-private emb staging in B0 (dead after phase 2b).
    // lane loads code (k0 + kc + lane>>3), floats (lane&7)*8..+8 -> coalesced 2xf4.
    const int k0 = wave * 256;
    const float* esrc = embv + (size_t)(k0 + (lane >> 3)) * 64 + (lane & 7) * 8;
    float* estw = B0 + wave * 1024 + (lane >> 3) * 64 + (lane & 7) * 8;
    {   // prologue: codes [k0, k0+8) -> half 0 (latency hides under A computation below)
        float4 sa = ldf4(esrc), sb = ldf4(esrc + 4);
        *(float4*)(estw) = sa; *(float4*)(estw + 4) = sb;
    }

    // A = ||z||^2 with numpy pairwise chain (8 strided accumulators, balanced tree), streamed
    float A;
    {
        float r[8];
        {
            float4 v0 = *(const float4*)&B1[lane * 68 + 0];
            float4 v1 = *(const float4*)&B1[lane * 68 + 4];
            r[0] = v0.x * v0.x; r[1] = v0.y * v0.y; r[2] = v0.z * v0.z; r[3] = v0.w * v0.w;
            r[4] = v1.x * v1.x; r[5] = v1.y * v1.y; r[6] = v1.z * v1.z; r[7] = v1.w * v1.w;
        }
        #pragma unroll
        for (int i = 8; i < 64; i += 8) {
            float4 v0 = *(const float4*)&B1[lane * 68 + i];
            float4 v1 = *(const float4*)&B1[lane * 68 + i + 4];
            float p0 = v0.x * v0.x, p1 = v0.y * v0.y, p2 = v0.z * v0.z, p3 = v0.w * v0.w;
            float p4 = v1.x * v1.x, p5 = v1.y * v1.y, p6 = v1.z * v1.z, p7 = v1.w * v1.w;
            r[0] = r[0] + p0; r[1] = r[1] + p1; r[2] = r[2] + p2; r[3] = r[3] + p3;
            r[4] = r[4] + p4; r[5] = r[5] + p5; r[6] = r[6] + p6; r[7] = r[7] + p7;
        }
        A = ((r[0] + r[1]) + (r[2] + r[3])) + ((r[4] + r[5]) + (r[6] + r[7]));
    }

    // ---- phase 4: scores over wave's 256-code slice, 8-code chunks; emb via staged LDS
    // (double-buffered halves), z quarters re-read from LDS. FMA order identical.
    float best = 3.4e38f;
    int bk = k0;
    #pragma unroll 1
    for (int kc = 0; kc < 256; kc += 8) {
        const int cur = (kc >> 3) & 1;
        float4 na, nb;
        if (kc < 248) {   // issue next chunk's loads; they fly under this chunk's FMAs
            na = ldf4(esrc + (size_t)(kc + 8) * 64);
            nb = ldf4(esrc + (size_t)(kc + 8) * 64 + 4);
        }
        float4 en03 = ldf4(env + k0 + kc);
        float4 en47 = ldf4(env + k0 + kc + 4);
        const float* ebase = B0 + wave * 1024 + cur * 512;
        float d0[8], d1[8], d2[8], d3[8];
        #pragma unroll
        for (int c = 0; c < 8; ++c) { d0[c] = 0.f; d1[c] = 0.f; d2[c] = 0.f; d3[c] = 0.f; }
        #pragma unroll
        for (int q = 0; q < 4; ++q) {
            float4 zq0 = *(const float4*)&B1[lane * 68 + q * 16];
            float4 zq1 = *(const float4*)&B1[lane * 68 + q * 16 + 4];
            float4 zq2 = *(const float4*)&B1[lane * 68 + q * 16 + 8];
            float4 zq3 = *(const float4*)&B1[lane * 68 + q * 16 + 12];
            #pragma unroll
            for (int c = 0; c < 8; ++c) {
                const float* ep = ebase + c * 64 + q * 16;
                float4 e0 = ldf4(ep), e1 = ldf4(ep + 4), e2 = ldf4(ep + 8), e3 = ldf4(ep + 12);
                d0[c] = __builtin_fmaf(zq0.x, e0.x, d0[c]);
                d1[c] = __builtin_fmaf(zq0.y, e0.y, d1[c]);
                d2[c] = __builtin_fmaf(zq0.z, e0.z, d2[c]);
                d3[c] = __builtin_fmaf(zq0.w, e0.w, d3[c]);
                d0[c] = __builtin_fmaf(zq1.x, e1.x, d0[c]);
                d1[c] = __builtin_fmaf(zq1.y, e1.y, d1[c]);
                d2[c] = __builtin_fmaf(zq1.z, e1.z, d2[c]);
                d3[c] = __builtin_fmaf(zq1.w, e1.w, d3[c]);
                d0[c] = __builtin_fmaf(zq2.x, e2.x, d0[c]);
                d1[c] = __builtin_fmaf(zq2.y, e2.y, d1[c]);
                d2[c] = __builtin_fmaf(zq2.z, e2.z, d2[c]);
                d3[c] = __builtin_fmaf(zq2.w, e2.w, d3[c]);
                d0[c] = __builtin_fmaf(zq3.x, e3.x, d0[c]);
                d1[c] = __builtin_fmaf(zq3.y, e3.y, d1[c]);
                d2[c] = __builtin_fmaf(zq3.z, e3.z, d2[c]);
                d3[c] = __builtin_fmaf(zq3.w, e3.w, d3[c]);
            }
        }
        float enb[8];
        *(float4*)&enb[0] = en03; *(float4*)&enb[4] = en47;
        #pragma unroll
        for (int c = 0; c < 8; ++c) {
            float dot = (d0[c] + d1[c]) + (d2[c] + d3[c]);
            float tt  = __builtin_fmaf(-2.0f, dot, A);
            float s   = tt + enb[c];
            if (s < best) { best = s; bk = k0 + kc + c; }
        }
        if (kc < 248) {
            float* stn = estw + ((cur ^ 1) * 512);
            *(float4*)(stn) = na; *(float4*)(stn + 4) = nb;
        }
    }
    __syncthreads();   // all waves done with B0 staging regions before cand reuse

    // ---- phase 5: cross-wave argmin (ascending wave => first-min); B0 dead -> cand storage
    float* cand_s = B0 + 64;
    int*   cand_k = ((int*)B0) + 320;
    int*   ixp    = (int*)B0;
    cand_s[wave * 64 + lane] = best;
    cand_k[wave * 64 + lane] = bk;
    __syncthreads();
    if (t < 64) {
        float s0 = cand_s[t];
        int   kk = cand_k[t];
        #pragma unroll
        for (int w2 = 1; w2 < 4; ++w2) {
            float sw = cand_s[w2 * 64 + t];
            if (sw < s0) { s0 = sw; kk = cand_k[w2 * 64 + t]; }
        }
        ixp[t] = kk;
        out[(size_t)NROWS * 64 + rowbase + t] = (float)kk;
    }
    __syncthreads();

    // ---- phase 6: recon = dec_out[idx], coalesced f4 store
    #pragma unroll
    for (int q = 0; q < 4; ++q) {
        int f = t + 256 * q;
        int r = f >> 4, c4 = f & 15;
        float4 v = ldf4(dec_out + (size_t)ixp[r] * 64 + c4 * 4);
        *(float4*)(out + (rowbase + r) * 64 + c4 * 4) = v;
    }
}

extern "C" void kernel_launch(void* const* d_in, const int* in_sizes, int n_in,
                              void* d_out, int out_size, void* d_ws, size_t ws_size,
                              hipStream_t stream) {
    const float* x   = (const float*)d_in[0];
    const float* We1 = (const float*)d_in[1];
    const float* be1 = (const float*)d_in[2];
    const float* We2 = (const float*)d_in[3];
    const float* be2 = (const float*)d_in[4];
    const float* We3 = (const float*)d_in[5];
    const float* be3 = (const float*)d_in[6];
    const float* emb = (const float*)d_in[7];
    const float* Wd1 = (const float*)d_in[8];
    const float* bd1 = (const float*)d_in[9];
    const float* Wd2 = (const float*)d_in[10];
    const float* bd2 = (const float*)d_in[11];
    const float* Wd3 = (const float*)d_in[12];
    const float* bd3 = (const float*)d_in[13];
    float* out = (float*)d_out;

    // ws layout (floats): dec_out[65536] | W2T[65536] | W1T[16384] | W3T[16384] | en[1024+pad]
    float* ws      = (float*)d_ws;
    float* dec_out = ws;
    float* W2T     = ws + 65536;
    float* W1T     = ws + 131072;
    float* W3T     = ws + 147456;
    float* en      = ws + 163840;   // en + 1 KB pad absorbs fold prefetch overrun

    prep_transpose<<<384, 256, 0, stream>>>(We1, We2, We3, W1T, W2T, W3T);
    prep_decoder<<<256, 256, 0, stream>>>(emb, Wd1, bd1, Wd2, bd2, Wd3, bd3, dec_out, en);
    vqvae_main<<<NROWS / 64, 256, 0, stream>>>(x, be1, be2, be3, W1T, W2T, W3T, emb, en,
                                               dec_out, out);
}

// Round 9
// 1269.645 us; speedup vs baseline: 6.3842x; 6.3842x over previous
//
#include <hip/hip_runtime.h>
#include <math.h>

#pragma clang fp contract(off)

#define NROWS 131072

// selu matching np: scale * where(x>0, x, alpha*expm1(x)), each op rounded separately
__device__ __forceinline__ float selu_f(float v) {
    float em  = expm1f(v);
    float neg = 1.6732632423543772f * em;
    float r   = v > 0.0f ? v : neg;
    return 1.0507009873554805f * r;
}

__device__ __forceinline__ float4 ldf4(const float* p) { return *(const float4*)p; }

__device__ __forceinline__ void ld4x4(float4* b, const float* p) {
    b[0] = ldf4(p); b[1] = ldf4(p + 4); b[2] = ldf4(p + 8); b[3] = ldf4(p + 12);
}

__device__ __forceinline__ void fma16a(float* a, const float4* w, float h) {
    a[0]  = __builtin_fmaf(w[0].x, h, a[0]);  a[1]  = __builtin_fmaf(w[0].y, h, a[1]);
    a[2]  = __builtin_fmaf(w[0].z, h, a[2]);  a[3]  = __builtin_fmaf(w[0].w, h, a[3]);
    a[4]  = __builtin_fmaf(w[1].x, h, a[4]);  a[5]  = __builtin_fmaf(w[1].y, h, a[5]);
    a[6]  = __builtin_fmaf(w[1].z, h, a[6]);  a[7]  = __builtin_fmaf(w[1].w, h, a[7]);
    a[8]  = __builtin_fmaf(w[2].x, h, a[8]);  a[9]  = __builtin_fmaf(w[2].y, h, a[9]);
    a[10] = __builtin_fmaf(w[2].z, h, a[10]); a[11] = __builtin_fmaf(w[2].w, h, a[11]);
    a[12] = __builtin_fmaf(w[3].x, h, a[12]); a[13] = __builtin_fmaf(w[3].y, h, a[13]);
    a[14] = __builtin_fmaf(w[3].z, h, a[14]); a[15] = __builtin_fmaf(w[3].w, h, a[15]);
}

// rotate step: issue next row's 4xf4 loads, then consume current buffer, then rotate in
__device__ __forceinline__ void step16(float* acc, float4* wb, const float* nextp, float h) {
    float4 t0 = ldf4(nextp), t1 = ldf4(nextp + 4), t2 = ldf4(nextp + 8), t3 = ldf4(nextp + 12);
    fma16a(acc, wb, h);
    wb[0] = t0; wb[1] = t1; wb[2] = t2; wb[3] = t3;
}

// 16 fmas from 4 explicit float4s (immediate-consume form, no rotate buffer)
__device__ __forceinline__ void fma16q(float* a, float4 w0, float4 w1, float4 w2, float4 w3, float h) {
    a[0]  = __builtin_fmaf(w0.x, h, a[0]);  a[1]  = __builtin_fmaf(w0.y, h, a[1]);
    a[2]  = __builtin_fmaf(w0.z, h, a[2]);  a[3]  = __builtin_fmaf(w0.w, h, a[3]);
    a[4]  = __builtin_fmaf(w1.x, h, a[4]);  a[5]  = __builtin_fmaf(w1.y, h, a[5]);
    a[6]  = __builtin_fmaf(w1.z, h, a[6]);  a[7]  = __builtin_fmaf(w1.w, h, a[7]);
    a[8]  = __builtin_fmaf(w2.x, h, a[8]);  a[9]  = __builtin_fmaf(w2.y, h, a[9]);
    a[10] = __builtin_fmaf(w2.z, h, a[10]); a[11] = __builtin_fmaf(w2.w, h, a[11]);
    a[12] = __builtin_fmaf(w3.x, h, a[12]); a[13] = __builtin_fmaf(w3.y, h, a[13]);
    a[14] = __builtin_fmaf(w3.z, h, a[14]); a[15] = __builtin_fmaf(w3.w, h, a[15]);
}

// direct global->LDS DMA: 16 B/lane, dest = wave-uniform LDS base + lane*16, src per-lane.
// Zero VGPR cost for the payload -> deep prefetch without register pressure.
typedef __attribute__((address_space(3))) unsigned int lds_u32;
typedef const __attribute__((address_space(1))) unsigned int glb_u32;
__device__ __forceinline__ void gll16(const float* g, float* l) {
    __builtin_amdgcn_global_load_lds((glb_u32*)g, (lds_u32*)l, 16, 0, 0);
}

// ---------- prep 1: W2 [256,256] -> W2T [j][c]; W3 [64,256] -> W3T [c][e]; W1 [256,64] -> W1T [j][c]
__global__ void prep_transpose(const float* __restrict__ W1, const float* __restrict__ W2,
                               const float* __restrict__ W3,
                               float* __restrict__ W1T, float* __restrict__ W2T,
                               float* __restrict__ W3T) {
    int id = blockIdx.x * 256 + threadIdx.x;
    if (id < 65536) { int c = id >> 8, j = id & 255; W2T[j * 256 + c] = W2[id]; }
    int id2 = id - 65536;
    if (id2 >= 0 && id2 < 16384) { int e = id2 >> 8, c = id2 & 255; W3T[c * 64 + e] = W3[id2]; }
    int id3 = id - 81920;
    if (id3 >= 0 && id3 < 16384) { int c = id3 >> 6, j = id3 & 63; W1T[j * 256 + c] = W1[id3]; }
}

// ---------- prep 2: decoder table dec_out[k] = decoder(emb[k]), and en[k] = ||emb_k||^2 ----------
__global__ void prep_decoder(const float* __restrict__ emb,
                             const float* __restrict__ Wd1, const float* __restrict__ bd1,
                             const float* __restrict__ Wd2, const float* __restrict__ bd2,
                             const float* __restrict__ Wd3, const float* __restrict__ bd3,
                             float* __restrict__ dec_out, float* __restrict__ en) {
    __shared__ float e[64];
    __shared__ float h1[256];
    __shared__ float h2[256];
    const int t = threadIdx.x; // 256 threads
    for (int kc = 0; kc < 4; ++kc) {
        const int k = blockIdx.x * 4 + kc;
        __syncthreads();
        if (t < 64) e[t] = emb[k * 64 + t];
        __syncthreads();
        {
            float acc = 0.0f;
            const float* w = Wd1 + t * 64;
            #pragma unroll
            for (int j = 0; j < 64; ++j) acc = __builtin_fmaf(w[j], e[j], acc);
            h1[t] = selu_f(acc + bd1[t]);
        }
        __syncthreads();
        {
            float acc = 0.0f;
            const float* w = Wd2 + t * 256;
            #pragma unroll 8
            for (int j = 0; j < 256; ++j) acc = __builtin_fmaf(w[j], h1[j], acc);
            h2[t] = selu_f(acc + bd2[t]);
        }
        __syncthreads();
        if (t < 64) {
            float acc = 0.0f;
            const float* w = Wd3 + t * 256;
            #pragma unroll 8
            for (int j = 0; j < 256; ++j) acc = __builtin_fmaf(w[j], h2[j], acc);
            dec_out[k * 64 + t] = acc + bd3[t];
        }
        if (t == 0) {
            float r[8];
            #pragma unroll
            for (int u = 0; u < 8; ++u) r[u] = e[u] * e[u];
            #pragma unroll
            for (int i = 8; i < 64; i += 8) {
                #pragma unroll
                for (int u = 0; u < 8; ++u) { float p = e[i + u] * e[i + u]; r[u] = r[u] + p; }
            }
            en[k] = ((r[0] + r[1]) + (r[2] + r[3])) + ((r[4] + r[5]) + (r[6] + r[7]));
        }
    }
}

// ---------- main kernel ----------
// 256 threads = 4 waves, 64 rows (lane = row).
// LAW (rounds 0-8): waves/EU = 256/VGPR_alloc; waves_per_eu min caps VGPR (min=2 -> 128).
// Round 8's reg-staged LDS pipeline exceeded 128 -> forced spill (15+ GB scratch). This round
// keeps the deep-prefetch idea but uses global_load_lds DMA: payload never touches VGPRs.
// Phases 2 & 4 consume one LDS half while the DMA fills the other; per-wave counted
// "s_waitcnt vmcnt(2)" keeps the 2 newest DMAs in flight (never drain mid-loop). en[] is
// pre-staged into LDS so the only in-loop VMEM is the DMA. FMA chain orders identical to
// round 6 -> bit-exact.
// LDS: B0 16 KB (xT -> fold stage -> emb DMA buf -> cand) + B1 17 KB (h1 -> z park)
//    + B2 16 KB (W2 DMA buf -> en table) = 49 KB.
__global__ __launch_bounds__(256) __attribute__((amdgpu_waves_per_eu(2, 8)))
void vqvae_main(const float* __restrict__ x,
                const float* __restrict__ b1, const float* __restrict__ b2,
                const float* __restrict__ b3,
                const float* __restrict__ W1T, const float* __restrict__ W2T,
                const float* __restrict__ W3T,
                const float* __restrict__ emb, const float* __restrict__ en,
                const float* __restrict__ dec_out, float* __restrict__ out) {
    __shared__ __align__(16) float B0[4096];
    __shared__ __align__(16) float B1[4352];
    __shared__ __align__(16) float B2[4096];

    const int t    = threadIdx.x;
    const int wave = t >> 6;      // 0..3
    const int lane = t & 63;
    const size_t rowbase = (size_t)blockIdx.x * 64;

    // opaque zero in a VGPR: keeps uniform loads on the vector pipe (vmcnt, pipelinable)
    int lz;
    asm volatile("v_mov_b32 %0, 0" : "=v"(lz));

    const float* W1Tv = W1T + lz;
    const float* W2Tv = W2T + lz;
    const float* W3Tv = W3T + lz;
    const float* b1v  = b1 + lz;
    const float* b2v  = b2 + lz;
    const float* b3v  = b3 + lz;
    const float* env  = en + lz;
    const float* embv = emb + lz;

    // ---- phase 0: stage x tile transposed into B0: xT[j][r]
    #pragma unroll
    for (int q = 0; q < 4; ++q) {
        int f = t + 256 * q;
        int r = f >> 4, c4 = f & 15;
        float4 v = ldf4(x + (rowbase + r) * 64 + c4 * 4);
        B0[(c4 * 4 + 0) * 64 + r] = v.x;
        B0[(c4 * 4 + 1) * 64 + r] = v.y;
        B0[(c4 * 4 + 2) * 64 + r] = v.z;
        B0[(c4 * 4 + 3) * 64 + r] = v.w;
    }
    __syncthreads();

    // persistent h2 accumulators: wave owns cols [64*wave, 64*wave+64)
    float acc2[64];
    #pragma unroll
    for (int u = 0; u < 64; ++u) acc2[u] = 0.0f;

    // ---- phases 1+2 fused, j-chunked: for each chunk cc, compute h1 cols [64cc,64cc+64)
    // into B1 (pair layout), then accumulate those 64 j's into acc2. j ascending overall.
    for (int cc = 0; cc < 4; ++cc) {
        // phase-1 chunk: wave computes h1 cols cg = 64cc + 16*wave .. +16 (chain: j=0..63 asc)
        {
            const float* wp = W1Tv + cc * 64 + wave * 16;   // row j at wp + j*256
            float4 A[4];
            ld4x4(A, wp);
            float acc[16];
            #pragma unroll
            for (int u = 0; u < 16; ++u) acc[u] = 0.0f;
            #pragma unroll 1
            for (int j = 0; j < 64; ++j) {
                const float* np = wp + (j + 1) * 256;  // j=63 overruns into W3T region (in-ws, unused)
                step16(acc, A, np, B0[j * 64 + lane]);
            }
            float bb[16];
            *(float4*)&bb[0]  = ldf4(b1v + cc * 64 + wave * 16);
            *(float4*)&bb[4]  = ldf4(b1v + cc * 64 + wave * 16 + 4);
            *(float4*)&bb[8]  = ldf4(b1v + cc * 64 + wave * 16 + 8);
            *(float4*)&bb[12] = ldf4(b1v + cc * 64 + wave * 16 + 12);
            float hv[16];
            #pragma unroll
            for (int u = 0; u < 16; ++u) hv[u] = selu_f(acc[u] + bb[u]);
            // pair layout: local j = 16*wave + u; B1[(jl>>1)*128 + 2*lane + (jl&1)]
            #pragma unroll
            for (int up = 0; up < 8; ++up) {
                *(float2*)&B1[(wave * 8 + up) * 128 + (lane << 1)] =
                    make_float2(hv[2 * up], hv[2 * up + 1]);
            }
        }
        __syncthreads();
        // phase-2 chunk: acc2[u] += sum over this chunk's 64 j's (ascending) of W2T[j][64w+u]*h1[j].
        // Weights arrive via global_load_lds DMA into the wave's private double-buffered B2
        // region (8 rows x 64 cols per half). Counted vmcnt keeps next-half DMAs in flight.
        {
            // lane l covers region floats [l*4, l*4+4): row = l>>4 (of 4), col = (l&15)*4
            const float* gsrc = W2Tv + (size_t)(cc * 64 + (lane >> 4)) * 256 + wave * 64 + (lane & 15) * 4;
            float* stA = B2 + wave * 1024;
            gll16(gsrc, stA);                 // sub-chunk 0, rows 0-3 -> half0[0:256)
            gll16(gsrc + 1024, stA + 256);    // sub-chunk 0, rows 4-7 -> half0[256:512)
            #pragma unroll 1
            for (int s = 0; s < 8; ++s) {
                if (s < 7) {
                    const float* ns = gsrc + (size_t)(s + 1) * 2048;
                    float* nd = stA + ((s + 1) & 1) * 512;
                    gll16(ns, nd);
                    gll16(ns + 1024, nd + 256);
                    asm volatile("s_waitcnt vmcnt(2)" ::: "memory");
                } else {
                    asm volatile("s_waitcnt vmcnt(0)" ::: "memory");
                }
                const float* wl = stA + (s & 1) * 512;   // [row 0..7][col 0..63]
                #pragma unroll
                for (int jj = 0; jj < 8; jj += 2) {
                    float2 h01 = *(const float2*)&B1[((s * 8 + jj) >> 1) * 128 + (lane << 1)];
                    const float* r0 = wl + jj * 64;
                    #pragma unroll
                    for (int qd = 0; qd < 4; ++qd) {
                        const float* p = r0 + qd * 16;
                        fma16q(acc2 + qd * 16, ldf4(p), ldf4(p + 4), ldf4(p + 8), ldf4(p + 12), h01.x);
                    }
                    const float* r1 = wl + (jj + 1) * 64;
                    #pragma unroll
                    for (int qd = 0; qd < 4; ++qd) {
                        const float* p = r1 + qd * 16;
                        fma16q(acc2 + qd * 16, ldf4(p), ldf4(p + 4), ldf4(p + 8), ldf4(p + 12), h01.y);
                    }
                }
            }
        }
        __syncthreads();   // h1 consumed; next chunk may overwrite (also guards B0 reuse later)
    }

    // h2 = selu(acc2 + b2) in place
    {
        #pragma unroll
        for (int qd = 0; qd < 4; ++qd) {
            float bb[16];
            *(float4*)&bb[0]  = ldf4(b2v + wave * 64 + qd * 16);
            *(float4*)&bb[4]  = ldf4(b2v + wave * 64 + qd * 16 + 4);
            *(float4*)&bb[8]  = ldf4(b2v + wave * 64 + qd * 16 + 8);
            *(float4*)&bb[12] = ldf4(b2v + wave * 64 + qd * 16 + 12);
            #pragma unroll
            for (int i = 0; i < 16; ++i)
                acc2[qd * 16 + i] = selu_f(acc2[qd * 16 + i] + bb[i]);
        }
    }

    // ---- phase 2b: layer-3 fold, staged per col-block g (= wave g's h2 cols), c ascending.
    // z = ((P0+P1)+(P2+P3)) + b3 (identical combine to all passing rounds)
    const int er = wave * 16;
    float s01[16], s23[16];
    for (int g = 0; g < 4; ++g) {
        if (wave == g) {
            #pragma unroll
            for (int u = 0; u < 64; ++u) B0[u * 64 + lane] = acc2[u];
        }
        __syncthreads();   // stage visible to all
        const float* w3p = W3Tv + g * 4096 + er;    // col (64g+c) at w3p + c*64
        float4 F0[4], F1[4];
        ld4x4(F0, w3p); ld4x4(F1, w3p + 64);
        float P[16];
        #pragma unroll
        for (int u = 0; u < 16; ++u) P[u] = 0.0f;
        #pragma unroll 1
        for (int c = 0; c < 64; c += 2) {
            const float* np = w3p + (c + 2) * 64;  // c=62: rows 64..65 overrun into en pad (in-ws)
            step16(P, F0, np,      B0[(c + 0) * 64 + lane]);
            step16(P, F1, np + 64, B0[(c + 1) * 64 + lane]);
        }
        if (g == 0) {
            #pragma unroll
            for (int u = 0; u < 16; ++u) s01[u] = P[u];
        } else if (g == 1) {
            #pragma unroll
            for (int u = 0; u < 16; ++u) s01[u] = s01[u] + P[u];
        } else if (g == 2) {
            #pragma unroll
            for (int u = 0; u < 16; ++u) s23[u] = P[u];
        } else {
            #pragma unroll
            for (int u = 0; u < 16; ++u) s23[u] = s23[u] + P[u];
        }
        __syncthreads();   // folds done before next wave overwrites stage
    }

    // ---- phase 3: z = (s01+s23)+b3; park z in LDS (zs[lane][e], stride 68 -> 2-way free b128)
    {
        float bb[16];
        *(float4*)&bb[0]  = ldf4(b3v + er);
        *(float4*)&bb[4]  = ldf4(b3v + er + 4);
        *(float4*)&bb[8]  = ldf4(b3v + er + 8);
        *(float4*)&bb[12] = ldf4(b3v + er + 12);
        float zv[16];
        #pragma unroll
        for (int u = 0; u < 16; ++u) zv[u] = (s01[u] + s23[u]) + bb[u];
        #pragma unroll
        for (int m = 0; m < 4; ++m)
            *(float4*)&B1[lane * 68 + er + m * 4] =
                make_float4(zv[4 * m], zv[4 * m + 1], zv[4 * m + 2], zv[4 * m + 3]);
    }
    __syncthreads();

    // ---- phase 4 setup. B2 (W2 staging, dead since phase 2b barriers) now holds the wave's
    // 256 en values so the score loop has ZERO non-DMA VMEM. Then prologue emb DMA chunk 0.
    const int k0 = wave * 256;
    {
        float4 ev = ldf4(env + k0 + lane * 4);
        *(float4*)&B2[wave * 256 + lane * 4] = ev;
    }
    const float* esrc = embv + (size_t)(k0 + (lane >> 4)) * 64 + (lane & 15) * 4;
    float* eA = B0 + wave * 1024;
    gll16(esrc, eA);               // codes 0-3 -> half0[0:256)
    gll16(esrc + 256, eA + 256);   // codes 4-7 -> half0[256:512)

    // A = ||z||^2 with numpy pairwise chain (8 strided accumulators, balanced tree), streamed.
    // (Also gives the prologue DMA time to land.)
    float A;
    {
        float r[8];
        {
            float4 v0 = *(const float4*)&B1[lane * 68 + 0];
            float4 v1 = *(const float4*)&B1[lane * 68 + 4];
            r[0] = v0.x * v0.x; r[1] = v0.y * v0.y; r[2] = v0.z * v0.z; r[3] = v0.w * v0.w;
            r[4] = v1.x * v1.x; r[5] = v1.y * v1.y; r[6] = v1.z * v1.z; r[7] = v1.w * v1.w;
        }
        #pragma unroll
        for (int i = 8; i < 64; i += 8) {
            float4 v0 = *(const float4*)&B1[lane * 68 + i];
            float4 v1 = *(const float4*)&B1[lane * 68 + i + 4];
            float p0 = v0.x * v0.x, p1 = v0.y * v0.y, p2 = v0.z * v0.z, p3 = v0.w * v0.w;
            float p4 = v1.x * v1.x, p5 = v1.y * v1.y, p6 = v1.z * v1.z, p7 = v1.w * v1.w;
            r[0] = r[0] + p0; r[1] = r[1] + p1; r[2] = r[2] + p2; r[3] = r[3] + p3;
            r[4] = r[4] + p4; r[5] = r[5] + p5; r[6] = r[6] + p6; r[7] = r[7] + p7;
        }
        A = ((r[0] + r[1]) + (r[2] + r[3])) + ((r[4] + r[5]) + (r[6] + r[7]));
    }

    // ---- phase 4: scores over wave's 256-code slice, 8-code chunks; emb via DMA-staged LDS
    // halves, en from LDS, z quarters re-read from LDS. FMA order identical to round 6.
    float best = 3.4e38f;
    int bk = k0;
    #pragma unroll 1
    for (int kc = 0; kc < 256; kc += 8) {
        const int cur = (kc >> 3) & 1;
        if (kc < 248) {   // DMA next chunk into the other half; keep it in flight (vmcnt(2))
            const float* ns = esrc + (size_t)(kc + 8) * 64;
            float* nd = eA + (cur ^ 1) * 512;
            gll16(ns, nd);
            gll16(ns + 256, nd + 256);
            asm volatile("s_waitcnt vmcnt(2)" ::: "memory");
        } else {
            asm volatile("s_waitcnt vmcnt(0)" ::: "memory");
        }
        const float* ebase = eA + cur * 512;
        float d0[8], d1[8], d2[8], d3[8];
        #pragma unroll
        for (int c = 0; c < 8; ++c) { d0[c] = 0.f; d1[c] = 0.f; d2[c] = 0.f; d3[c] = 0.f; }
        #pragma unroll
        for (int q = 0; q < 4; ++q) {
            float4 zq0 = *(const float4*)&B1[lane * 68 + q * 16];
            float4 zq1 = *(const float4*)&B1[lane * 68 + q * 16 + 4];
            float4 zq2 = *(const float4*)&B1[lane * 68 + q * 16 + 8];
            float4 zq3 = *(const float4*)&B1[lane * 68 + q * 16 + 12];
            #pragma unroll
            for (int c = 0; c < 8; ++c) {
                const float* ep = ebase + c * 64 + q * 16;
                float4 e0 = ldf4(ep), e1 = ldf4(ep + 4), e2 = ldf4(ep + 8), e3 = ldf4(ep + 12);
                d0[c] = __builtin_fmaf(zq0.x, e0.x, d0[c]);
                d1[c] = __builtin_fmaf(zq0.y, e0.y, d1[c]);
                d2[c] = __builtin_fmaf(zq0.z, e0.z, d2[c]);
                d3[c] = __builtin_fmaf(zq0.w, e0.w, d3[c]);
                d0[c] = __builtin_fmaf(zq1.x, e1.x, d0[c]);
                d1[c] = __builtin_fmaf(zq1.y, e1.y, d1[c]);
                d2[c] = __builtin_fmaf(zq1.z, e1.z, d2[c]);
                d3[c] = __builtin_fmaf(zq1.w, e1.w, d3[c]);
                d0[c] = __builtin_fmaf(zq2.x, e2.x, d0[c]);
                d1[c] = __builtin_fmaf(zq2.y, e2.y, d1[c]);
                d2[c] = __builtin_fmaf(zq2.z, e2.z, d2[c]);
                d3[c] = __builtin_fmaf(zq2.w, e2.w, d3[c]);
                d0[c] = __builtin_fmaf(zq3.x, e3.x, d0[c]);
                d1[c] = __builtin_fmaf(zq3.y, e3.y, d1[c]);
                d2[c] = __builtin_fmaf(zq3.z, e3.z, d2[c]);
                d3[c] = __builtin_fmaf(zq3.w, e3.w, d3[c]);
            }
        }
        float enb[8];
        *(float4*)&enb[0] = *(const float4*)&B2[wave * 256 + kc];
        *(float4*)&enb[4] = *(const float4*)&B2[wave * 256 + kc + 4];
        #pragma unroll
        for (int c = 0; c < 8; ++c) {
            float dot = (d0[c] + d1[c]) + (d2[c] + d3[c]);
            float tt  = __builtin_fmaf(-2.0f, dot, A);
            float s   = tt + enb[c];
            if (s < best) { best = s; bk = k0 + kc + c; }
        }
    }
    __syncthreads();   // all waves done with B0 staging regions before cand reuse

    // ---- phase 5: cross-wave argmin (ascending wave => first-min); B0 dead -> cand storage
    float* cand_s = B0 + 64;
    int*   cand_k = ((int*)B0) + 320;
    int*   ixp    = (int*)B0;
    cand_s[wave * 64 + lane] = best;
    cand_k[wave * 64 + lane] = bk;
    __syncthreads();
    if (t < 64) {
        float s0 = cand_s[t];
        int   kk = cand_k[t];
        #pragma unroll
        for (int w2 = 1; w2 < 4; ++w2) {
            float sw = cand_s[w2 * 64 + t];
            if (sw < s0) { s0 = sw; kk = cand_k[w2 * 64 + t]; }
        }
        ixp[t] = kk;
        out[(size_t)NROWS * 64 + rowbase + t] = (float)kk;
    }
    __syncthreads();

    // ---- phase 6: recon = dec_out[idx], coalesced f4 store
    #pragma unroll
    for (int q = 0; q < 4; ++q) {
        int f = t + 256 * q;
        int r = f >> 4, c4 = f & 15;
        float4 v = ldf4(dec_out + (size_t)ixp[r] * 64 + c4 * 4);
        *(float4*)(out + (rowbase + r) * 64 + c4 * 4) = v;
    }
}

extern "C" void kernel_launch(void* const* d_in, const int* in_sizes, int n_in,
                              void* d_out, int out_size, void* d_ws, size_t ws_size,
                              hipStream_t stream) {
    const float* x   = (const float*)d_in[0];
    const float* We1 = (const float*)d_in[1];
    const float* be1 = (const float*)d_in[2];
    const float* We2 = (const float*)d_in[3];
    const float* be2 = (const float*)d_in[4];
    const float* We3 = (const float*)d_in[5];
    const float* be3 = (const float*)d_in[6];
    const float* emb = (const float*)d_in[7];
    const float* Wd1 = (const float*)d_in[8];
    const float* bd1 = (const float*)d_in[9];
    const float* Wd2 = (const float*)d_in[10];
    const float* bd2 = (const float*)d_in[11];
    const float* Wd3 = (const float*)d_in[12];
    const float* bd3 = (const float*)d_in[13];
    float* out = (float*)d_out;

    // ws layout (floats): dec_out[65536] | W2T[65536] | W1T[16384] | W3T[16384] | en[1024+pad]
    float* ws      = (float*)d_ws;
    float* dec_out = ws;
    float* W2T     = ws + 65536;
    float* W1T     = ws + 131072;
    float* W3T     = ws + 147456;
    float* en      = ws + 163840;   // en + 1 KB pad absorbs fold prefetch overrun

    prep_transpose<<<384, 256, 0, stream>>>(We1, We2, We3, W1T, W2T, W3T);
    prep_decoder<<<256, 256, 0, stream>>>(emb, Wd1, bd1, Wd2, bd2, Wd3, bd3, dec_out, en);
    vqvae_main<<<NROWS / 64, 256, 0, stream>>>(x, be1, be2, be3, W1T, W2T, W3T, emb, en,
                                               dec_out, out);
}

// Round 10
// 1142.008 us; speedup vs baseline: 7.0978x; 1.1118x over previous
//
#include <hip/hip_runtime.h>
#include <math.h>

#pragma clang fp contract(off)

#define NROWS 131072

// selu matching np: scale * where(x>0, x, alpha*expm1(x)), each op rounded separately
__device__ __forceinline__ float selu_f(float v) {
    float em  = expm1f(v);
    float neg = 1.6732632423543772f * em;
    float r   = v > 0.0f ? v : neg;
    return 1.0507009873554805f * r;
}

__device__ __forceinline__ float4 ldf4(const float* p) { return *(const float4*)p; }

__device__ __forceinline__ void ld2x4(float4* b, const float* p) { b[0] = ldf4(p); b[1] = ldf4(p + 4); }

__device__ __forceinline__ void ld4x4(float4* b, const float* p) {
    b[0] = ldf4(p); b[1] = ldf4(p + 4); b[2] = ldf4(p + 8); b[3] = ldf4(p + 12);
}

__device__ __forceinline__ void fma8a(float* a, const float4* w, float h) {
    a[0] = __builtin_fmaf(w[0].x, h, a[0]);  a[1] = __builtin_fmaf(w[0].y, h, a[1]);
    a[2] = __builtin_fmaf(w[0].z, h, a[2]);  a[3] = __builtin_fmaf(w[0].w, h, a[3]);
    a[4] = __builtin_fmaf(w[1].x, h, a[4]);  a[5] = __builtin_fmaf(w[1].y, h, a[5]);
    a[6] = __builtin_fmaf(w[1].z, h, a[6]);  a[7] = __builtin_fmaf(w[1].w, h, a[7]);
}

__device__ __forceinline__ void fma16a(float* a, const float4* w, float h) {
    a[0]  = __builtin_fmaf(w[0].x, h, a[0]);  a[1]  = __builtin_fmaf(w[0].y, h, a[1]);
    a[2]  = __builtin_fmaf(w[0].z, h, a[2]);  a[3]  = __builtin_fmaf(w[0].w, h, a[3]);
    a[4]  = __builtin_fmaf(w[1].x, h, a[4]);  a[5]  = __builtin_fmaf(w[1].y, h, a[5]);
    a[6]  = __builtin_fmaf(w[1].z, h, a[6]);  a[7]  = __builtin_fmaf(w[1].w, h, a[7]);
    a[8]  = __builtin_fmaf(w[2].x, h, a[8]);  a[9]  = __builtin_fmaf(w[2].y, h, a[9]);
    a[10] = __builtin_fmaf(w[2].z, h, a[10]); a[11] = __builtin_fmaf(w[2].w, h, a[11]);
    a[12] = __builtin_fmaf(w[3].x, h, a[12]); a[13] = __builtin_fmaf(w[3].y, h, a[13]);
    a[14] = __builtin_fmaf(w[3].z, h, a[14]); a[15] = __builtin_fmaf(w[3].w, h, a[15]);
}

// rotate step: issue next row's 4xf4 loads, then consume current buffer, then rotate in
__device__ __forceinline__ void step16(float* acc, float4* wb, const float* nextp, float h) {
    float4 t0 = ldf4(nextp), t1 = ldf4(nextp + 4), t2 = ldf4(nextp + 8), t3 = ldf4(nextp + 12);
    fma16a(acc, wb, h);
    wb[0] = t0; wb[1] = t1; wb[2] = t2; wb[3] = t3;
}

// direct global->LDS DMA: 16 B/lane, dest = wave-uniform LDS base + lane*16, src per-lane.
// Zero VGPR cost for the payload -> deep prefetch without register pressure.
typedef __attribute__((address_space(3))) unsigned int lds_u32;
typedef const __attribute__((address_space(1))) unsigned int glb_u32;
__device__ __forceinline__ void gll16(const float* g, float* l) {
    __builtin_amdgcn_global_load_lds((glb_u32*)g, (lds_u32*)l, 16, 0, 0);
}

// ---------- prep 1: W2 [256,256] -> W2T [j][c]; W3 [64,256] -> W3T [c][e]; W1 [256,64] -> W1T [j][c]
__global__ void prep_transpose(const float* __restrict__ W1, const float* __restrict__ W2,
                               const float* __restrict__ W3,
                               float* __restrict__ W1T, float* __restrict__ W2T,
                               float* __restrict__ W3T) {
    int id = blockIdx.x * 256 + threadIdx.x;
    if (id < 65536) { int c = id >> 8, j = id & 255; W2T[j * 256 + c] = W2[id]; }
    int id2 = id - 65536;
    if (id2 >= 0 && id2 < 16384) { int e = id2 >> 8, c = id2 & 255; W3T[c * 64 + e] = W3[id2]; }
    int id3 = id - 81920;
    if (id3 >= 0 && id3 < 16384) { int c = id3 >> 6, j = id3 & 63; W1T[j * 256 + c] = W1[id3]; }
}

// ---------- prep 2: decoder table dec_out[k] = decoder(emb[k]), and en[k] = ||emb_k||^2 ----------
__global__ void prep_decoder(const float* __restrict__ emb,
                             const float* __restrict__ Wd1, const float* __restrict__ bd1,
                             const float* __restrict__ Wd2, const float* __restrict__ bd2,
                             const float* __restrict__ Wd3, const float* __restrict__ bd3,
                             float* __restrict__ dec_out, float* __restrict__ en) {
    __shared__ float e[64];
    __shared__ float h1[256];
    __shared__ float h2[256];
    const int t = threadIdx.x; // 256 threads
    for (int kc = 0; kc < 4; ++kc) {
        const int k = blockIdx.x * 4 + kc;
        __syncthreads();
        if (t < 64) e[t] = emb[k * 64 + t];
        __syncthreads();
        {
            float acc = 0.0f;
            const float* w = Wd1 + t * 64;
            #pragma unroll
            for (int j = 0; j < 64; ++j) acc = __builtin_fmaf(w[j], e[j], acc);
            h1[t] = selu_f(acc + bd1[t]);
        }
        __syncthreads();
        {
            float acc = 0.0f;
            const float* w = Wd2 + t * 256;
            #pragma unroll 8
            for (int j = 0; j < 256; ++j) acc = __builtin_fmaf(w[j], h1[j], acc);
            h2[t] = selu_f(acc + bd2[t]);
        }
        __syncthreads();
        if (t < 64) {
            float acc = 0.0f;
            const float* w = Wd3 + t * 256;
            #pragma unroll 8
            for (int j = 0; j < 256; ++j) acc = __builtin_fmaf(w[j], h2[j], acc);
            dec_out[k * 64 + t] = acc + bd3[t];
        }
        if (t == 0) {
            float r[8];
            #pragma unroll
            for (int u = 0; u < 8; ++u) r[u] = e[u] * e[u];
            #pragma unroll
            for (int i = 8; i < 64; i += 8) {
                #pragma unroll
                for (int u = 0; u < 8; ++u) { float p = e[i + u] * e[i + u]; r[u] = r[u] + p; }
            }
            en[k] = ((r[0] + r[1]) + (r[2] + r[3])) + ((r[4] + r[5]) + (r[6] + r[7]));
        }
    }
}

// ---------- main kernel ----------
// 256 threads = 4 waves, 64 rows (lane = row).
// LAW (rounds 0-9): waves/EU = 256/VGPR_alloc. Round 9 (VGPR=100, DMA pipeline) = 1270 us at
// 2 waves/EU, VALUBusy 47%. This round targets 3 waves/EU: waves_per_eu(3,8) caps VGPR at ~84;
// peak pressure cut to fit:
//   - phase 2 consume: 8-col groups (ld2x4+fma8a, live window 16->8); per-acc2 chain over j
//     unchanged -> bit-exact.
//   - phase 2b: immediate-consume ld4x4+fma16a (no rotate temps); c ascending unchanged.
//     W3T is L1-resident; 3-wave TLP covers the exposure (10% of FMAs).
//   - phase 4: 4-code chunks (d-accums 32->16; round-3-verified structure), DMA 1 gll16/chunk,
//     vmcnt(1).
//   - bias pointers de-laundered (cold scalar loads, frees pointer VGPRs).
// LDS 49 KB -> 3 blocks/CU (147 KB); VGPR<=84 -> 3 waves/EU. Fallback if spill (WRITE >200MB):
// revert min to 2, keep reductions.
__global__ __launch_bounds__(256) __attribute__((amdgpu_waves_per_eu(3, 8)))
void vqvae_main(const float* __restrict__ x,
                const float* __restrict__ b1, const float* __restrict__ b2,
                const float* __restrict__ b3,
                const float* __restrict__ W1T, const float* __restrict__ W2T,
                const float* __restrict__ W3T,
                const float* __restrict__ emb, const float* __restrict__ en,
                const float* __restrict__ dec_out, float* __restrict__ out) {
    __shared__ __align__(16) float B0[4096];
    __shared__ __align__(16) float B1[4352];
    __shared__ __align__(16) float B2[4096];

    const int t    = threadIdx.x;
    const int wave = t >> 6;      // 0..3
    const int lane = t & 63;
    const size_t rowbase = (size_t)blockIdx.x * 64;

    // opaque zero in a VGPR: keeps hot-stream loads on the vector pipe (vmcnt, pipelinable)
    int lz;
    asm volatile("v_mov_b32 %0, 0" : "=v"(lz));

    const float* W1Tv = W1T + lz;
    const float* W2Tv = W2T + lz;
    const float* W3Tv = W3T + lz;
    const float* env  = en + lz;
    const float* embv = emb + lz;

    // ---- phase 0: stage x tile transposed into B0: xT[j][r]
    #pragma unroll
    for (int q = 0; q < 4; ++q) {
        int f = t + 256 * q;
        int r = f >> 4, c4 = f & 15;
        float4 v = ldf4(x + (rowbase + r) * 64 + c4 * 4);
        B0[(c4 * 4 + 0) * 64 + r] = v.x;
        B0[(c4 * 4 + 1) * 64 + r] = v.y;
        B0[(c4 * 4 + 2) * 64 + r] = v.z;
        B0[(c4 * 4 + 3) * 64 + r] = v.w;
    }
    __syncthreads();

    // persistent h2 accumulators: wave owns cols [64*wave, 64*wave+64)
    float acc2[64];
    #pragma unroll
    for (int u = 0; u < 64; ++u) acc2[u] = 0.0f;

    // ---- phases 1+2 fused, j-chunked: for each chunk cc, compute h1 cols [64cc,64cc+64)
    // into B1 (pair layout), then accumulate those 64 j's into acc2. j ascending overall.
    for (int cc = 0; cc < 4; ++cc) {
        // phase-1 chunk: wave computes h1 cols cg = 64cc + 16*wave .. +16 (chain: j=0..63 asc)
        {
            const float* wp = W1Tv + cc * 64 + wave * 16;   // row j at wp + j*256
            float4 A[4];
            ld4x4(A, wp);
            float acc[16];
            #pragma unroll
            for (int u = 0; u < 16; ++u) acc[u] = 0.0f;
            #pragma unroll 1
            for (int j = 0; j < 64; ++j) {
                const float* np = wp + (j + 1) * 256;  // j=63 overruns into W3T region (in-ws, unused)
                step16(acc, A, np, B0[j * 64 + lane]);
            }
            float bb[16];
            *(float4*)&bb[0]  = ldf4(b1 + cc * 64 + wave * 16);
            *(float4*)&bb[4]  = ldf4(b1 + cc * 64 + wave * 16 + 4);
            *(float4*)&bb[8]  = ldf4(b1 + cc * 64 + wave * 16 + 8);
            *(float4*)&bb[12] = ldf4(b1 + cc * 64 + wave * 16 + 12);
            float hv[16];
            #pragma unroll
            for (int u = 0; u < 16; ++u) hv[u] = selu_f(acc[u] + bb[u]);
            // pair layout: local j = 16*wave + u; B1[(jl>>1)*128 + 2*lane + (jl&1)]
            #pragma unroll
            for (int up = 0; up < 8; ++up) {
                *(float2*)&B1[(wave * 8 + up) * 128 + (lane << 1)] =
                    make_float2(hv[2 * up], hv[2 * up + 1]);
            }
        }
        __syncthreads();
        // phase-2 chunk: acc2[u] += sum over this chunk's 64 j's (ascending) of W2T[j][64w+u]*h1[j].
        // Weights arrive via global_load_lds DMA into the wave's private double-buffered B2
        // region (8 rows x 64 cols per half). Counted vmcnt keeps next-half DMAs in flight.
        // Consume in 8-col groups (fma8a): per-acc2[u] chain over j unchanged.
        {
            // lane l covers region floats [l*4, l*4+4): row = l>>4 (of 4), col = (l&15)*4
            const float* gsrc = W2Tv + (size_t)(cc * 64 + (lane >> 4)) * 256 + wave * 64 + (lane & 15) * 4;
            float* stA = B2 + wave * 1024;
            gll16(gsrc, stA);                 // sub-chunk 0, rows 0-3 -> half0[0:256)
            gll16(gsrc + 1024, stA + 256);    // sub-chunk 0, rows 4-7 -> half0[256:512)
            #pragma unroll 1
            for (int s = 0; s < 8; ++s) {
                if (s < 7) {
                    const float* ns = gsrc + (size_t)(s + 1) * 2048;
                    float* nd = stA + ((s + 1) & 1) * 512;
                    gll16(ns, nd);
                    gll16(ns + 1024, nd + 256);
                    asm volatile("s_waitcnt vmcnt(2)" ::: "memory");
                } else {
                    asm volatile("s_waitcnt vmcnt(0)" ::: "memory");
                }
                const float* wl = stA + (s & 1) * 512;   // [row 0..7][col 0..63]
                #pragma unroll
                for (int jj = 0; jj < 8; jj += 2) {
                    float2 h01 = *(const float2*)&B1[((s * 8 + jj) >> 1) * 128 + (lane << 1)];
                    const float* r0 = wl + jj * 64;
                    #pragma unroll
                    for (int g8 = 0; g8 < 8; ++g8) {
                        float4 wv[2];
                        ld2x4(wv, r0 + g8 * 8);
                        fma8a(acc2 + g8 * 8, wv, h01.x);
                    }
                    const float* r1 = wl + (jj + 1) * 64;
                    #pragma unroll
                    for (int g8 = 0; g8 < 8; ++g8) {
                        float4 wv[2];
                        ld2x4(wv, r1 + g8 * 8);
                        fma8a(acc2 + g8 * 8, wv, h01.y);
                    }
                }
            }
        }
        __syncthreads();   // h1 consumed; next chunk may overwrite (also guards B0 reuse later)
    }

    // h2 = selu(acc2 + b2) in place
    {
        #pragma unroll
        for (int qd = 0; qd < 4; ++qd) {
            float bb[16];
            *(float4*)&bb[0]  = ldf4(b2 + wave * 64 + qd * 16);
            *(float4*)&bb[4]  = ldf4(b2 + wave * 64 + qd * 16 + 4);
            *(float4*)&bb[8]  = ldf4(b2 + wave * 64 + qd * 16 + 8);
            *(float4*)&bb[12] = ldf4(b2 + wave * 64 + qd * 16 + 12);
            #pragma unroll
            for (int i = 0; i < 16; ++i)
                acc2[qd * 16 + i] = selu_f(acc2[qd * 16 + i] + bb[i]);
        }
    }

    // ---- phase 2b: layer-3 fold, staged per col-block g (= wave g's h2 cols), c ascending,
    // immediate-consume (W3T is L1-resident; no rotate temps -> low VGPR pressure).
    // z = ((P0+P1)+(P2+P3)) + b3 (identical combine to all passing rounds)
    const int er = wave * 16;
    float s01[16], s23[16];
    for (int g = 0; g < 4; ++g) {
        if (wave == g) {
            #pragma unroll
            for (int u = 0; u < 64; ++u) B0[u * 64 + lane] = acc2[u];
        }
        __syncthreads();   // stage visible to all
        const float* w3p = W3Tv + g * 4096 + er;    // col (64g+c) at w3p + c*64
        float P[16];
        #pragma unroll
        for (int u = 0; u < 16; ++u) P[u] = 0.0f;
        #pragma unroll 1
        for (int c = 0; c < 64; ++c) {
            float4 F[4];
            ld4x4(F, w3p + c * 64);
            fma16a(P, F, B0[c * 64 + lane]);
        }
        if (g == 0) {
            #pragma unroll
            for (int u = 0; u < 16; ++u) s01[u] = P[u];
        } else if (g == 1) {
            #pragma unroll
            for (int u = 0; u < 16; ++u) s01[u] = s01[u] + P[u];
        } else if (g == 2) {
            #pragma unroll
            for (int u = 0; u < 16; ++u) s23[u] = P[u];
        } else {
            #pragma unroll
            for (int u = 0; u < 16; ++u) s23[u] = s23[u] + P[u];
        }
        __syncthreads();   // folds done before next wave overwrites stage
    }

    // ---- phase 3: z = (s01+s23)+b3; park z in LDS (zs[lane][e], stride 68 -> 2-way free b128)
    {
        float bb[16];
        *(float4*)&bb[0]  = ldf4(b3 + er);
        *(float4*)&bb[4]  = ldf4(b3 + er + 4);
        *(float4*)&bb[8]  = ldf4(b3 + er + 8);
        *(float4*)&bb[12] = ldf4(b3 + er + 12);
        float zv[16];
        #pragma unroll
        for (int u = 0; u < 16; ++u) zv[u] = (s01[u] + s23[u]) + bb[u];
        #pragma unroll
        for (int m = 0; m < 4; ++m)
            *(float4*)&B1[lane * 68 + er + m * 4] =
                make_float4(zv[4 * m], zv[4 * m + 1], zv[4 * m + 2], zv[4 * m + 3]);
    }
    __syncthreads();

    // ---- phase 4 setup. B2 (W2 staging, dead since phase 2b barriers) holds the wave's 256 en
    // values so the score loop has ZERO non-DMA VMEM. Then prologue emb DMA chunk 0 (4 codes).
    const int k0 = wave * 256;
    {
        float4 ev = ldf4(env + k0 + lane * 4);
        *(float4*)&B2[wave * 256 + lane * 4] = ev;
    }
    // lane l covers chunk floats [4l, 4l+4): code = l>>4 (of 4), float (l&15)*4
    const float* esrc = embv + (size_t)(k0 + (lane >> 4)) * 64 + (lane & 15) * 4;
    float* eA = B0 + wave * 1024;
    gll16(esrc, eA);               // codes 0-3 -> half0[0:256)

    // A = ||z||^2 with numpy pairwise chain (8 strided accumulators, balanced tree), streamed.
    // (Also gives the prologue DMA time to land.)
    float A;
    {
        float r[8];
        {
            float4 v0 = *(const float4*)&B1[lane * 68 + 0];
            float4 v1 = *(const float4*)&B1[lane * 68 + 4];
            r[0] = v0.x * v0.x; r[1] = v0.y * v0.y; r[2] = v0.z * v0.z; r[3] = v0.w * v0.w;
            r[4] = v1.x * v1.x; r[5] = v1.y * v1.y; r[6] = v1.z * v1.z; r[7] = v1.w * v1.w;
        }
        #pragma unroll
        for (int i = 8; i < 64; i += 8) {
            float4 v0 = *(const float4*)&B1[lane * 68 + i];
            float4 v1 = *(const float4*)&B1[lane * 68 + i + 4];
            float p0 = v0.x * v0.x, p1 = v0.y * v0.y, p2 = v0.z * v0.z, p3 = v0.w * v0.w;
            float p4 = v1.x * v1.x, p5 = v1.y * v1.y, p6 = v1.z * v1.z, p7 = v1.w * v1.w;
            r[0] = r[0] + p0; r[1] = r[1] + p1; r[2] = r[2] + p2; r[3] = r[3] + p3;
            r[4] = r[4] + p4; r[5] = r[5] + p5; r[6] = r[6] + p6; r[7] = r[7] + p7;
        }
        A = ((r[0] + r[1]) + (r[2] + r[3])) + ((r[4] + r[5]) + (r[6] + r[7]));
    }

    // ---- phase 4: scores over wave's 256-code slice, 4-code chunks (16 d-accums, round-3
    // structure); emb via DMA-staged LDS halves, en from LDS, z quarters re-read from LDS.
    // Per-code FMA order identical to all passing rounds.
    float best = 3.4e38f;
    int bk = k0;
    #pragma unroll 1
    for (int kc = 0; kc < 256; kc += 4) {
        const int cur = (kc >> 2) & 1;
        if (kc < 252) {   // DMA next chunk into the other half; keep it in flight (vmcnt(1))
            gll16(esrc + (size_t)(kc + 4) * 64, eA + (cur ^ 1) * 256);
            asm volatile("s_waitcnt vmcnt(1)" ::: "memory");
        } else {
            asm volatile("s_waitcnt vmcnt(0)" ::: "memory");
        }
        const float* ebase = eA + cur * 256;
        float d0[4], d1[4], d2[4], d3[4];
        #pragma unroll
        for (int c = 0; c < 4; ++c) { d0[c] = 0.f; d1[c] = 0.f; d2[c] = 0.f; d3[c] = 0.f; }
        #pragma unroll
        for (int q = 0; q < 4; ++q) {
            float4 zq0 = *(const float4*)&B1[lane * 68 + q * 16];
            float4 zq1 = *(const float4*)&B1[lane * 68 + q * 16 + 4];
            float4 zq2 = *(const float4*)&B1[lane * 68 + q * 16 + 8];
            float4 zq3 = *(const float4*)&B1[lane * 68 + q * 16 + 12];
            #pragma unroll
            for (int c = 0; c < 4; ++c) {
                const float* ep = ebase + c * 64 + q * 16;
                float4 e0 = ldf4(ep), e1 = ldf4(ep + 4), e2 = ldf4(ep + 8), e3 = ldf4(ep + 12);
                d0[c] = __builtin_fmaf(zq0.x, e0.x, d0[c]);
                d1[c] = __builtin_fmaf(zq0.y, e0.y, d1[c]);
                d2[c] = __builtin_fmaf(zq0.z, e0.z, d2[c]);
                d3[c] = __builtin_fmaf(zq0.w, e0.w, d3[c]);
                d0[c] = __builtin_fmaf(zq1.x, e1.x, d0[c]);
                d1[c] = __builtin_fmaf(zq1.y, e1.y, d1[c]);
                d2[c] = __builtin_fmaf(zq1.z, e1.z, d2[c]);
                d3[c] = __builtin_fmaf(zq1.w, e1.w, d3[c]);
                d0[c] = __builtin_fmaf(zq2.x, e2.x, d0[c]);
                d1[c] = __builtin_fmaf(zq2.y, e2.y, d1[c]);
                d2[c] = __builtin_fmaf(zq2.z, e2.z, d2[c]);
                d3[c] = __builtin_fmaf(zq2.w, e2.w, d3[c]);
                d0[c] = __builtin_fmaf(zq3.x, e3.x, d0[c]);
                d1[c] = __builtin_fmaf(zq3.y, e3.y, d1[c]);
                d2[c] = __builtin_fmaf(zq3.z, e3.z, d2[c]);
                d3[c] = __builtin_fmaf(zq3.w, e3.w, d3[c]);
            }
        }
        float enb[4];
        *(float4*)&enb[0] = *(const float4*)&B2[wave * 256 + kc];
        #pragma unroll
        for (int c = 0; c < 4; ++c) {
            float dot = (d0[c] + d1[c]) + (d2[c] + d3[c]);
            float tt  = __builtin_fmaf(-2.0f, dot, A);
            float s   = tt + enb[c];
            if (s < best) { best = s; bk = k0 + kc + c; }
        }
    }
    __syncthreads();   // all waves done with B0 staging regions before cand reuse

    // ---- phase 5: cross-wave argmin (ascending wave => first-min); B0 dead -> cand storage
    float* cand_s = B0 + 64;
    int*   cand_k = ((int*)B0) + 320;
    int*   ixp    = (int*)B0;
    cand_s[wave * 64 + lane] = best;
    cand_k[wave * 64 + lane] = bk;
    __syncthreads();
    if (t < 64) {
        float s0 = cand_s[t];
        int   kk = cand_k[t];
        #pragma unroll
        for (int w2 = 1; w2 < 4; ++w2) {
            float sw = cand_s[w2 * 64 + t];
            if (sw < s0) { s0 = sw; kk = cand_k[w2 * 64 + t]; }
        }
        ixp[t] = kk;
        out[(size_t)NROWS * 64 + rowbase + t] = (float)kk;
    }
    __syncthreads();

    // ---- phase 6: recon = dec_out[idx], coalesced f4 store
    #pragma unroll
    for (int q = 0; q < 4; ++q) {
        int f = t + 256 * q;
        int r = f >> 4, c4 = f & 15;
        float4 v = ldf4(dec_out + (size_t)ixp[r] * 64 + c4 * 4);
        *(float4*)(out + (rowbase + r) * 64 + c4 * 4) = v;
    }
}

extern "C" void kernel_launch(void* const* d_in, const int* in_sizes, int n_in,
                              void* d_out, int out_size, void* d_ws, size_t ws_size,
                              hipStream_t stream) {
    const float* x   = (const float*)d_in[0];
    const float* We1 = (const float*)d_in[1];
    const float* be1 = (const float*)d_in[2];
    const float* We2 = (const float*)d_in[3];
    const float* be2 = (const float*)d_in[4];
    const float* We3 = (const float*)d_in[5];
    const float* be3 = (const float*)d_in[6];
    const float* emb = (const float*)d_in[7];
    const float* Wd1 = (const float*)d_in[8];
    const float* bd1 = (const float*)d_in[9];
    const float* Wd2 = (const float*)d_in[10];
    const float* bd2 = (const float*)d_in[11];
    const float* Wd3 = (const float*)d_in[12];
    const float* bd3 = (const float*)d_in[13];
    float* out = (float*)d_out;

    // ws layout (floats): dec_out[65536] | W2T[65536] | W1T[16384] | W3T[16384] | en[1024+pad]
    float* ws      = (float*)d_ws;
    float* dec_out = ws;
    float* W2T     = ws + 65536;
    float* W1T     = ws + 131072;
    float* W3T     = ws + 147456;
    float* en      = ws + 163840;   // en + 1 KB pad absorbs phase-1 prefetch overrun

    prep_transpose<<<384, 256, 0, stream>>>(We1, We2, We3, W1T, W2T, W3T);
    prep_decoder<<<256, 256, 0, stream>>>(emb, Wd1, bd1, Wd2, bd2, Wd3, bd3, dec_out, en);
    vqvae_main<<<NROWS / 64, 256, 0, stream>>>(x, be1, be2, be3, W1T, W2T, W3T, emb, en,
                                               dec_out, out);
}